// Round 1
// baseline (260.680 us; speedup 1.0000x reference)
//
#include <hip/hip_runtime.h>
#include <cstdint>
#include <cstddef>

#define BB 256
#define TB 2048
#define NROWS (BB*TB)          // 524288 rows of [64]

// ---- workspace layout (bytes) ----
#define OFF_X      0ull
#define SZ_X       ((size_t)NROWS*64*4)            // 134217728 raw x_proj
#define OFF_PART   (OFF_X + SZ_X)
#define SZ_PART    ((size_t)(NROWS/64)*128*4)      // 4 MiB block partial sums
#define OFF_STAT   (OFF_PART + SZ_PART)
#define SZ_STAT    (128*8)                          // f64 col sums / sumsq
#define OFF_PARAM  (OFF_STAT + SZ_STAT)             // scale[64] shift[64] thresh[1024]
#define SZ_PARAM   ((size_t)(64+64+1024)*4)
#define OFF_MASK   ((OFF_PARAM + SZ_PARAM + 255ull) & ~255ull)
#define SZ_MASK    ((size_t)NROWS*8)                // 4 MiB spike masks [t][b]
#define OFF_CUR2   (OFF_MASK + SZ_MASK)
#define SZ_CUR2    ((size_t)NROWS*4*4)              // 8 MiB cur2 [t][b][4]

// ============ K1: x_proj = kin @ W^T (raw) + per-block col sum/sumsq ============
__global__ __launch_bounds__(256) void k1_gemm(const float* __restrict__ kin,
                                               const float* __restrict__ Wsp,
                                               float* __restrict__ xproj,
                                               float* __restrict__ partials) {
  __shared__ float As[64*65];
  __shared__ float Ws[64*65];
  const int tid = threadIdx.x;
  const int blk = blockIdx.x;
  const size_t r0 = (size_t)blk * 64;

  for (int i = tid; i < 1024; i += 256) {
    const int row = i >> 4, c4 = (i & 15) << 2;
    float4 a = *(const float4*)(kin + (r0 + row) * 64 + c4);
    As[row*65 + c4 + 0] = a.x; As[row*65 + c4 + 1] = a.y;
    As[row*65 + c4 + 2] = a.z; As[row*65 + c4 + 3] = a.w;
    float4 w = *(const float4*)(Wsp + row * 64 + c4);
    Ws[row*65 + c4 + 0] = w.x; Ws[row*65 + c4 + 1] = w.y;
    Ws[row*65 + c4 + 2] = w.z; Ws[row*65 + c4 + 3] = w.w;
  }
  __syncthreads();

  const int ty = tid >> 4, tx = tid & 15;   // rows 4*ty.., cols 4*tx..
  float acc[4][4];
  #pragma unroll
  for (int i = 0; i < 4; ++i)
    #pragma unroll
    for (int j = 0; j < 4; ++j) acc[i][j] = 0.f;

  #pragma unroll 4
  for (int c = 0; c < 64; ++c) {
    float av[4], wv[4];
    #pragma unroll
    for (int i = 0; i < 4; ++i) av[i] = As[(4*ty + i)*65 + c];
    #pragma unroll
    for (int j = 0; j < 4; ++j) wv[j] = Ws[(4*tx + j)*65 + c];
    #pragma unroll
    for (int i = 0; i < 4; ++i)
      #pragma unroll
      for (int j = 0; j < 4; ++j)
        acc[i][j] = fmaf(av[i], wv[j], acc[i][j]);
  }

  #pragma unroll
  for (int i = 0; i < 4; ++i) {
    float4 o = make_float4(acc[i][0], acc[i][1], acc[i][2], acc[i][3]);
    *(float4*)(xproj + (r0 + 4*ty + i) * 64 + 4*tx) = o;
  }
  __syncthreads();            // reuse As/Ws for stat reduction

  #pragma unroll
  for (int j = 0; j < 4; ++j) {
    float s = acc[0][j] + acc[1][j] + acc[2][j] + acc[3][j];
    float q = acc[0][j]*acc[0][j] + acc[1][j]*acc[1][j]
            + acc[2][j]*acc[2][j] + acc[3][j]*acc[3][j];
    As[ty*64 + 4*tx + j] = s;
    Ws[ty*64 + 4*tx + j] = q;
  }
  __syncthreads();
  if (tid < 64) {
    float s = 0.f, q = 0.f;
    #pragma unroll
    for (int g = 0; g < 16; ++g) { s += As[g*64 + tid]; q += Ws[g*64 + tid]; }
    partials[(size_t)blk*128 + tid]      = s;
    partials[(size_t)blk*128 + 64 + tid] = q;
  }
}

// ============ K2a: deterministic f64 reduction of partials ============
__global__ __launch_bounds__(256) void k2a_reduce(const float* __restrict__ partials,
                                                  double* __restrict__ statd) {
  __shared__ double sd[256];
  const int idx = blockIdx.x;              // 0..127
  double acc = 0.0;
  for (int k = threadIdx.x; k < NROWS/64; k += 256)
    acc += (double)partials[(size_t)k*128 + idx];
  sd[threadIdx.x] = acc;
  __syncthreads();
  for (int s = 128; s > 0; s >>= 1) {
    if (threadIdx.x < s) sd[threadIdx.x] += sd[threadIdx.x + s];
    __syncthreads();
  }
  if (threadIdx.x == 0) statd[idx] = sd[0];
}

// ============ K2b: BN scale/shift + dynamic thresholds ============
__global__ __launch_bounds__(256) void k2b_final(const double* __restrict__ statd,
                                                 const float* __restrict__ gamma,
                                                 const float* __restrict__ beta,
                                                 const float* __restrict__ tda,
                                                 const float* __restrict__ Wtda,
                                                 const float* __restrict__ btda,
                                                 float* __restrict__ param) {
  const int tid = threadIdx.x;
  if (tid < 64) {
    double mean = statd[tid] / (double)NROWS;
    double ex2  = statd[64 + tid] / (double)NROWS;
    double var  = ex2 - mean * mean;
    double sc   = (double)gamma[tid] / sqrt(var + 1e-5);
    param[tid]      = (float)sc;
    param[64 + tid] = (float)((double)beta[tid] - mean * sc);
  }
  const int b = tid;                       // 256 threads = 256 batch rows
  #pragma unroll
  for (int j = 0; j < 4; ++j) {
    double acc = (double)btda[j];
    for (int k = 0; k < 50; ++k)
      acc += (double)tda[b*50 + k] * (double)Wtda[j*50 + k];
    double sig = 1.0 / (1.0 + exp(-acc));
    param[128 + b*4 + j] = (float)(1.0 + 0.5 * sig);
  }
}

// ============ K3: layer-1 LIF scan, wave per b, lane = channel h ============
#define U3 32
__global__ __launch_bounds__(64) void k3_scan1(const float* __restrict__ xproj,
                                               const float* __restrict__ param,
                                               unsigned long long* __restrict__ masks) {
  const int b = blockIdx.x, h = threadIdx.x;
  const float sc = param[h], sh = param[64 + h];
  const float* xr = xproj + (size_t)b * TB * 64 + h;
  float mem = 0.f;
  float xa[U3], xb[U3];

  #pragma unroll
  for (int i = 0; i < U3; ++i) xa[i] = xr[(size_t)i * 64];

  for (int t0 = 0; t0 < TB; t0 += 2*U3) {
    #pragma unroll
    for (int i = 0; i < U3; ++i) xb[i] = xr[(size_t)(t0 + U3 + i) * 64];
    #pragma unroll
    for (int i = 0; i < U3; ++i) {
      float x = fmaf(xa[i], sc, sh);
      mem = fmaf(mem, 0.9f, x);
      const bool sp = (mem >= 1.0f);
      unsigned long long m = __ballot(sp);
      mem = sp ? 0.f : mem;
      if (h == 0) masks[(size_t)(t0 + i) * BB + b] = m;
    }
    if (t0 + 2*U3 < TB) {
      #pragma unroll
      for (int i = 0; i < U3; ++i) xa[i] = xr[(size_t)(t0 + 2*U3 + i) * 64];
    }
    #pragma unroll
    for (int i = 0; i < U3; ++i) {
      float x = fmaf(xb[i], sc, sh);
      mem = fmaf(mem, 0.9f, x);
      const bool sp = (mem >= 1.0f);
      unsigned long long m = __ballot(sp);
      mem = sp ? 0.f : mem;
      if (h == 0) masks[(size_t)(t0 + U3 + i) * BB + b] = m;
    }
  }
}

// ============ K4: cur2[t][b][:] = (spk1 @ Wc^T) @ lateral from bitmasks ============
__global__ __launch_bounds__(256) void k4_cur2(const unsigned long long* __restrict__ masks,
                                               const float* __restrict__ Wc,
                                               const float* __restrict__ lat,
                                               float* __restrict__ cur2) {
  __shared__ float WcL[256];
  __shared__ float latL[16];
  const int tid = threadIdx.x;
  WcL[tid] = Wc[tid];
  if (tid < 16) latL[tid] = lat[tid];
  __syncthreads();

  const size_t gid = (size_t)blockIdx.x * 256 + tid;   // = t*256 + b
  const unsigned long long m = masks[gid];
  float v0 = 0.f, v1 = 0.f, v2 = 0.f, v3 = 0.f;
  #pragma unroll
  for (int hh = 0; hh < 64; ++hh) {
    const float bit = (float)((unsigned)((m >> hh) & 1ull));
    v0 = fmaf(bit, WcL[hh],       v0);
    v1 = fmaf(bit, WcL[64 + hh],  v1);
    v2 = fmaf(bit, WcL[128 + hh], v2);
    v3 = fmaf(bit, WcL[192 + hh], v3);
  }
  float4 o;
  { float c = v0*latL[0];  c = fmaf(v1, latL[4],  c); c = fmaf(v2, latL[8],  c); c = fmaf(v3, latL[12], c); o.x = c; }
  { float c = v0*latL[1];  c = fmaf(v1, latL[5],  c); c = fmaf(v2, latL[9],  c); c = fmaf(v3, latL[13], c); o.y = c; }
  { float c = v0*latL[2];  c = fmaf(v1, latL[6],  c); c = fmaf(v2, latL[10], c); c = fmaf(v3, latL[14], c); o.z = c; }
  { float c = v0*latL[3];  c = fmaf(v1, latL[7],  c); c = fmaf(v2, latL[11], c); c = fmaf(v3, latL[15], c); o.w = c; }
  *(float4*)(cur2 + gid * 4) = o;
}

// ============ K5: layer-2 LIF scan, thread per (b, class) ============
#define U5 32
__global__ __launch_bounds__(64) void k5_scan2(const float* __restrict__ cur2,
                                               const float* __restrict__ param,
                                               float* __restrict__ out) {
  const int g = blockIdx.x * 64 + threadIdx.x;   // 0..1023 = b*4 + j
  const float th = param[128 + g];
  const float* cr = cur2 + g;                    // step stride 1024 floats
  float mem = 0.f, s = 0.f;
  float xa[U5], xb[U5];

  #pragma unroll
  for (int i = 0; i < U5; ++i) xa[i] = cr[(size_t)i * 1024];

  for (int t0 = 0; t0 < TB; t0 += 2*U5) {
    #pragma unroll
    for (int i = 0; i < U5; ++i) xb[i] = cr[(size_t)(t0 + U5 + i) * 1024];
    #pragma unroll
    for (int i = 0; i < U5; ++i) {
      mem = fmaf(mem, 0.9f, xa[i]);
      const bool sp = (mem >= th);
      s += sp ? 1.0f : 0.0f;
      mem = sp ? 0.f : mem;
    }
    if (t0 + 2*U5 < TB) {
      #pragma unroll
      for (int i = 0; i < U5; ++i) xa[i] = cr[(size_t)(t0 + 2*U5 + i) * 1024];
    }
    #pragma unroll
    for (int i = 0; i < U5; ++i) {
      mem = fmaf(mem, 0.9f, xb[i]);
      const bool sp = (mem >= th);
      s += sp ? 1.0f : 0.0f;
      mem = sp ? 0.f : mem;
    }
  }
  out[g] = s;
}

extern "C" void kernel_launch(void* const* d_in, const int* in_sizes, int n_in,
                              void* d_out, int out_size, void* d_ws, size_t ws_size,
                              hipStream_t stream) {
  const float* kin   = (const float*)d_in[0];
  const float* tda   = (const float*)d_in[1];
  const float* Wsp   = (const float*)d_in[2];
  const float* gamma = (const float*)d_in[3];
  const float* beta  = (const float*)d_in[4];
  const float* Wc    = (const float*)d_in[5];
  const float* lat   = (const float*)d_in[6];
  const float* Wtda  = (const float*)d_in[7];
  const float* btda  = (const float*)d_in[8];

  char* ws = (char*)d_ws;
  float*  xproj    = (float*)(ws + OFF_X);
  float*  partials = (float*)(ws + OFF_PART);
  double* statd    = (double*)(ws + OFF_STAT);
  float*  param    = (float*)(ws + OFF_PARAM);
  unsigned long long* masks = (unsigned long long*)(ws + OFF_MASK);
  float*  cur2     = (float*)(ws + OFF_CUR2);
  float*  out      = (float*)d_out;

  k1_gemm <<<dim3(NROWS/64), dim3(256), 0, stream>>>(kin, Wsp, xproj, partials);
  k2a_reduce<<<dim3(128),    dim3(256), 0, stream>>>(partials, statd);
  k2b_final <<<dim3(1),      dim3(256), 0, stream>>>(statd, gamma, beta, tda, Wtda, btda, param);
  k3_scan1 <<<dim3(BB),      dim3(64),  0, stream>>>(xproj, param, masks);
  k4_cur2  <<<dim3(NROWS/256), dim3(256), 0, stream>>>(masks, Wc, lat, cur2);
  k5_scan2 <<<dim3(16),      dim3(64),  0, stream>>>(cur2, param, out);
}

// Round 3
// 165.856 us; speedup vs baseline: 1.5717x; 1.5717x over previous
//
#include <hip/hip_runtime.h>
#include <cstdint>
#include <cstddef>

#define BB 256
#define TB 2048
#define NROWS (BB*TB)          // 524288 rows of [64]
#define R1 128                 // rows per k1 block
#define NBLK1 (NROWS/R1)       // 4096

typedef float f32x4 __attribute__((ext_vector_type(4)));

// ---- workspace layout (bytes) ----
#define OFF_X      0ull
#define SZ_X       ((size_t)NROWS*64*4)            // 128 MiB raw x_proj [bt][h]
#define OFF_PART   (OFF_X + SZ_X)
#define SZ_PART    ((size_t)128*NBLK1*4)           // 2 MiB partials [ch][blk]
#define OFF_STAT   (OFF_PART + SZ_PART)
#define SZ_STAT    (128*8)                         // f64 col sums / sumsq
#define OFF_PARAM  (OFF_STAT + SZ_STAT)            // scale[64] shift[64] thresh[1024]
#define SZ_PARAM   ((size_t)(64+64+1024)*4)
#define OFF_MASK   ((OFF_PARAM + SZ_PARAM + 255ull) & ~255ull)
#define SZ_MASK    ((size_t)NROWS*8)               // 4 MiB spike masks [b][t]
#define OFF_CUR2   (OFF_MASK + SZ_MASK)
#define SZ_CUR2    ((size_t)NROWS*4*4)             // 8 MiB cur2T [b*4+j][t]

// ============ K1: x_proj = kin @ W^T (raw) + per-block col sum/sumsq ============
// 128 rows x 64 cols per block; thread tile 4 rows x 8 cols; swizzled b128 LDS.
__global__ __launch_bounds__(256, 3) void k1_gemm(const float* __restrict__ kin,
                                                  const float* __restrict__ Wsp,
                                                  float* __restrict__ xproj,
                                                  float* __restrict__ partials) {
  __shared__ float4 As[R1 * 16];   // 32 KB, [r][cc ^ ((r>>2)&7)]
  __shared__ float4 Ws4[64 * 16];  // 16 KB, [h][cc ^ ((h>>2)&7)]
  const int tid = threadIdx.x;
  const size_t r0 = (size_t)blockIdx.x * R1;

  // stage A: 2048 float4, 8 per thread, coalesced; nontemporal (streamed once)
  const f32x4* kin4 = (const f32x4*)(kin + r0 * 64);
  #pragma unroll
  for (int k = 0; k < 8; ++k) {
    int idx = k * 256 + tid;
    int r = idx >> 4, cc = idx & 15;
    f32x4 v = __builtin_nontemporal_load(&kin4[idx]);
    As[r * 16 + (cc ^ ((r >> 2) & 7))] = make_float4(v.x, v.y, v.z, v.w);
  }
  const float4* W4 = (const float4*)Wsp;
  #pragma unroll
  for (int k = 0; k < 4; ++k) {
    int idx = k * 256 + tid;
    int h = idx >> 4, cc = idx & 15;
    Ws4[h * 16 + (cc ^ ((h >> 2) & 7))] = W4[idx];
  }
  __syncthreads();

  const int ty = tid >> 3;   // 0..31 -> rows 4*ty..+3
  const int tx = tid & 7;    // cols 4*tx..+3 and 32+4*tx..+3
  float acc[4][8];
  #pragma unroll
  for (int i = 0; i < 4; ++i)
    #pragma unroll
    for (int j = 0; j < 8; ++j) acc[i][j] = 0.f;

  #pragma unroll 1
  for (int cc = 0; cc < 16; ++cc) {
    float4 av[4], wl[4], wh[4];
    #pragma unroll
    for (int i = 0; i < 4; ++i) av[i] = As[(4 * ty + i) * 16 + (cc ^ (ty & 7))];
    #pragma unroll
    for (int j = 0; j < 4; ++j) {
      wl[j] = Ws4[(4 * tx + j) * 16 + (cc ^ tx)];
      wh[j] = Ws4[(32 + 4 * tx + j) * 16 + (cc ^ tx)];
    }
    #pragma unroll
    for (int i = 0; i < 4; ++i)
      #pragma unroll
      for (int j = 0; j < 4; ++j) {
        // c ascending within chunk -> overall c = 0..63 sequential (matches ref ordering)
        acc[i][j] = fmaf(av[i].x, wl[j].x, acc[i][j]);
        acc[i][j] = fmaf(av[i].y, wl[j].y, acc[i][j]);
        acc[i][j] = fmaf(av[i].z, wl[j].z, acc[i][j]);
        acc[i][j] = fmaf(av[i].w, wl[j].w, acc[i][j]);
        acc[i][4 + j] = fmaf(av[i].x, wh[j].x, acc[i][4 + j]);
        acc[i][4 + j] = fmaf(av[i].y, wh[j].y, acc[i][4 + j]);
        acc[i][4 + j] = fmaf(av[i].z, wh[j].z, acc[i][4 + j]);
        acc[i][4 + j] = fmaf(av[i].w, wh[j].w, acc[i][4 + j]);
      }
  }

  #pragma unroll
  for (int i = 0; i < 4; ++i) {
    const size_t row = r0 + 4 * ty + i;
    *(float4*)(xproj + row * 64 + 4 * tx) =
        make_float4(acc[i][0], acc[i][1], acc[i][2], acc[i][3]);
    *(float4*)(xproj + row * 64 + 32 + 4 * tx) =
        make_float4(acc[i][4], acc[i][5], acc[i][6], acc[i][7]);
  }

  __syncthreads();                 // all waves done reading As/Ws4
  float* Sm = (float*)As;          // [64][33]
  float* Sq = Sm + 64 * 33;
  #pragma unroll
  for (int j = 0; j < 8; ++j) {
    const int col = (j < 4) ? (4 * tx + j) : (32 + 4 * tx + (j - 4));
    float s = acc[0][j] + acc[1][j] + acc[2][j] + acc[3][j];
    float q = acc[0][j] * acc[0][j] + acc[1][j] * acc[1][j]
            + acc[2][j] * acc[2][j] + acc[3][j] * acc[3][j];
    Sm[col * 33 + ty] = s;
    Sq[col * 33 + ty] = q;
  }
  __syncthreads();
  if (tid < 64) {
    float s = 0.f, q = 0.f;
    #pragma unroll
    for (int g = 0; g < 32; ++g) { s += Sm[tid * 33 + g]; q += Sq[tid * 33 + g]; }
    partials[(size_t)tid * NBLK1 + blockIdx.x]        = s;
    partials[(size_t)(64 + tid) * NBLK1 + blockIdx.x] = q;
  }
}

// ============ K2a: deterministic f64 reduction (coalesced rows) ============
__global__ __launch_bounds__(256) void k2a_reduce(const float* __restrict__ partials,
                                                  double* __restrict__ statd) {
  __shared__ double sd[256];
  const int idx = blockIdx.x;              // 0..127
  double acc = 0.0;
  for (int k = threadIdx.x; k < NBLK1; k += 256)
    acc += (double)partials[(size_t)idx * NBLK1 + k];
  sd[threadIdx.x] = acc;
  __syncthreads();
  for (int s = 128; s > 0; s >>= 1) {
    if (threadIdx.x < s) sd[threadIdx.x] += sd[threadIdx.x + s];
    __syncthreads();
  }
  if (threadIdx.x == 0) statd[idx] = sd[0];
}

// ============ K2b: BN scale/shift + dynamic thresholds ============
__global__ __launch_bounds__(256) void k2b_final(const double* __restrict__ statd,
                                                 const float* __restrict__ gamma,
                                                 const float* __restrict__ beta,
                                                 const float* __restrict__ tda,
                                                 const float* __restrict__ Wtda,
                                                 const float* __restrict__ btda,
                                                 float* __restrict__ param) {
  const int tid = threadIdx.x;
  if (tid < 64) {
    double mean = statd[tid] / (double)NROWS;
    double ex2  = statd[64 + tid] / (double)NROWS;
    double var  = ex2 - mean * mean;
    double sc   = (double)gamma[tid] / sqrt(var + 1e-5);
    param[tid]      = (float)sc;
    param[64 + tid] = (float)((double)beta[tid] - mean * sc);
  }
  const int b = tid;
  #pragma unroll
  for (int j = 0; j < 4; ++j) {
    double acc = (double)btda[j];
    for (int k = 0; k < 50; ++k)
      acc += (double)tda[b * 50 + k] * (double)Wtda[j * 50 + k];
    double sig = 1.0 / (1.0 + exp(-acc));
    param[128 + b * 4 + j] = (float)(1.0 + 0.5 * sig);
  }
}

// ============ K3: layer-1 LIF scan, wave per b, lane = channel h ============
// short chain: sp = (mem>=1) ; mem' = sp ? x_next : fma(mem,0.9,x_next)  (bit-identical)
#define K3_LOAD(BUF, TBASE)                         \
  { _Pragma("unroll") for (int i_ = 0; i_ < 64; ++i_) \
      BUF[i_] = xr[(size_t)((TBASE) + i_) * 64]; }

#define K3_CHUNK(CUR, NXT0, TBASE)                                   \
  { unsigned long long keep = 0;                                     \
    _Pragma("unroll") for (int i_ = 0; i_ < 64; ++i_) {              \
      bool sp = (mem >= 1.0f);                                       \
      unsigned long long mb = __ballot(sp);                          \
      if (h == i_) keep = mb;                                        \
      float xrn = (i_ < 63) ? CUR[(i_ + 1) & 63] : (NXT0);           \
      float xn = fmaf(xrn, sc, sh);                                  \
      mem = sp ? xn : fmaf(mem, 0.9f, xn);                           \
    }                                                                \
    masksB[(size_t)b * TB + (TBASE) + h] = keep; }

__global__ __launch_bounds__(64) void k3_scan1(const float* __restrict__ xproj,
                                               const float* __restrict__ param,
                                               unsigned long long* __restrict__ masksB) {
  const int b = blockIdx.x, h = threadIdx.x;
  const float sc = param[h], sh = param[64 + h];
  const float* xr = xproj + (size_t)b * TB * 64 + h;
  float xa[64], xb[64];

  K3_LOAD(xa, 0)
  float mem = fmaf(xa[0], sc, sh);   // t=0 post-add state

  #pragma unroll 1
  for (int t0 = 0; t0 < TB; t0 += 128) {
    K3_LOAD(xb, t0 + 64)
    K3_CHUNK(xa, xb[0], t0)
    if (t0 + 128 < TB) { K3_LOAD(xa, t0 + 128) }
    K3_CHUNK(xb, xa[0], t0 + 64)    // final chunk: trailing xa[0] is dead
  }
}

// ============ K4: cur2T[(b*4+j)][t] from bitmasks (grid over b) ============
__global__ __launch_bounds__(256) void k4_cur2(const unsigned long long* __restrict__ masksB,
                                               const float* __restrict__ Wc,
                                               const float* __restrict__ lat,
                                               float* __restrict__ cur2T) {
  __shared__ float WcL[256];
  __shared__ float latL[16];
  const int tid = threadIdx.x, b = blockIdx.x;
  WcL[tid] = Wc[tid];
  if (tid < 16) latL[tid] = lat[tid];
  __syncthreads();

  #pragma unroll 1
  for (int c = 0; c < 8; ++c) {
    const int t = c * 256 + tid;
    const unsigned long long m = masksB[(size_t)b * TB + t];
    const unsigned lo = (unsigned)m, hi = (unsigned)(m >> 32);
    float v0 = 0.f, v1 = 0.f, v2 = 0.f, v3 = 0.f;
    #pragma unroll
    for (int hh = 0; hh < 32; ++hh) {
      const float bit = (float)((lo >> hh) & 1u);
      v0 = fmaf(bit, WcL[hh],       v0);
      v1 = fmaf(bit, WcL[64 + hh],  v1);
      v2 = fmaf(bit, WcL[128 + hh], v2);
      v3 = fmaf(bit, WcL[192 + hh], v3);
    }
    #pragma unroll
    for (int hh = 32; hh < 64; ++hh) {
      const float bit = (float)((hi >> (hh - 32)) & 1u);
      v0 = fmaf(bit, WcL[hh],       v0);
      v1 = fmaf(bit, WcL[64 + hh],  v1);
      v2 = fmaf(bit, WcL[128 + hh], v2);
      v3 = fmaf(bit, WcL[192 + hh], v3);
    }
    float o0, o1, o2, o3;
    { float cx = v0 * latL[0];  cx = fmaf(v1, latL[4],  cx); cx = fmaf(v2, latL[8],  cx); cx = fmaf(v3, latL[12], cx); o0 = cx; }
    { float cx = v0 * latL[1];  cx = fmaf(v1, latL[5],  cx); cx = fmaf(v2, latL[9],  cx); cx = fmaf(v3, latL[13], cx); o1 = cx; }
    { float cx = v0 * latL[2];  cx = fmaf(v1, latL[6],  cx); cx = fmaf(v2, latL[10], cx); cx = fmaf(v3, latL[14], cx); o2 = cx; }
    { float cx = v0 * latL[3];  cx = fmaf(v1, latL[7],  cx); cx = fmaf(v2, latL[11], cx); cx = fmaf(v3, latL[15], cx); o3 = cx; }
    cur2T[(size_t)(b * 4 + 0) * TB + t] = o0;
    cur2T[(size_t)(b * 4 + 1) * TB + t] = o1;
    cur2T[(size_t)(b * 4 + 2) * TB + t] = o2;
    cur2T[(size_t)(b * 4 + 3) * TB + t] = o3;
  }
}

// ============ K5: layer-2 LIF scan, thread per (b, class), contiguous reads ============
#define K5_LOAD(BUF, TBASE)                                              \
  { _Pragma("unroll") for (int k_ = 0; k_ < 16; ++k_) {                  \
      float4 v = cr[((TBASE) >> 2) + k_];                                \
      BUF[4 * k_] = v.x; BUF[4 * k_ + 1] = v.y;                          \
      BUF[4 * k_ + 2] = v.z; BUF[4 * k_ + 3] = v.w; } }

#define K5_CHUNK(CUR, NXT0)                                   \
  { _Pragma("unroll") for (int i_ = 0; i_ < 64; ++i_) {       \
      bool sp = (mem >= th);                                  \
      cnt += sp ? 1u : 0u;                                    \
      float xn = (i_ < 63) ? CUR[(i_ + 1) & 63] : (NXT0);     \
      mem = sp ? xn : fmaf(mem, 0.9f, xn);                    \
    } }

__global__ __launch_bounds__(64) void k5_scan2(const float* __restrict__ cur2T,
                                               const float* __restrict__ param,
                                               float* __restrict__ out) {
  const int g = blockIdx.x * 64 + threadIdx.x;   // 0..1023 = b*4 + j
  const float th = param[128 + g];
  const float4* cr = (const float4*)(cur2T + (size_t)g * TB);
  float ca[64], cb[64];

  K5_LOAD(ca, 0)
  float mem = ca[0];
  unsigned cnt = 0;

  #pragma unroll 1
  for (int t0 = 0; t0 < TB; t0 += 128) {
    K5_LOAD(cb, t0 + 64)
    K5_CHUNK(ca, cb[0])
    if (t0 + 128 < TB) { K5_LOAD(ca, t0 + 128) }
    K5_CHUNK(cb, ca[0])
  }
  out[g] = (float)cnt;
}

extern "C" void kernel_launch(void* const* d_in, const int* in_sizes, int n_in,
                              void* d_out, int out_size, void* d_ws, size_t ws_size,
                              hipStream_t stream) {
  const float* kin   = (const float*)d_in[0];
  const float* tda   = (const float*)d_in[1];
  const float* Wsp   = (const float*)d_in[2];
  const float* gamma = (const float*)d_in[3];
  const float* beta  = (const float*)d_in[4];
  const float* Wc    = (const float*)d_in[5];
  const float* lat   = (const float*)d_in[6];
  const float* Wtda  = (const float*)d_in[7];
  const float* btda  = (const float*)d_in[8];

  char* ws = (char*)d_ws;
  float*  xproj    = (float*)(ws + OFF_X);
  float*  partials = (float*)(ws + OFF_PART);
  double* statd    = (double*)(ws + OFF_STAT);
  float*  param    = (float*)(ws + OFF_PARAM);
  unsigned long long* masksB = (unsigned long long*)(ws + OFF_MASK);
  float*  cur2T    = (float*)(ws + OFF_CUR2);
  float*  out      = (float*)d_out;

  k1_gemm  <<<dim3(NBLK1), dim3(256), 0, stream>>>(kin, Wsp, xproj, partials);
  k2a_reduce<<<dim3(128),  dim3(256), 0, stream>>>(partials, statd);
  k2b_final<<<dim3(1),     dim3(256), 0, stream>>>(statd, gamma, beta, tda, Wtda, btda, param);
  k3_scan1 <<<dim3(BB),    dim3(64),  0, stream>>>(xproj, param, masksB);
  k4_cur2  <<<dim3(BB),    dim3(256), 0, stream>>>(masksB, Wc, lat, cur2T);
  k5_scan2 <<<dim3(16),    dim3(64),  0, stream>>>(cur2T, param, out);
}